// Round 1
// baseline (1832.108 us; speedup 1.0000x reference)
//
#include <hip/hip_runtime.h>
#include <math.h>

// Problem constants (fixed by the reference): B=256, S=2048, I=32, H=128, O=1
#define B_ 256
#define S_ 2048
#define I_ 32
#define H_ 128

// Barrier WITHOUT vmcnt(0) drain (HIP __syncthreads waits vmcnt(0) before
// s_barrier, which would stall on our in-flight x prefetch + score stores
// every step). LDS visibility only needs lgkmcnt(0). CK-style idiom; empty
// asm memory clobbers pin compiler ordering around the intrinsic barrier.
__device__ __forceinline__ void sync_lds() {
    asm volatile("" ::: "memory");
    asm volatile("s_waitcnt lgkmcnt(0)" ::: "memory");
    __builtin_amdgcn_s_barrier();
    asm volatile("" ::: "memory");
}

// tanh(z) = 1 - 2/(e^{2z}+1); exact limits at +-inf, abs err ~1e-7.
__device__ __forceinline__ float fast_tanh(float z) {
    float e = __expf(2.0f * z);
    return 1.0f - 2.0f / (e + 1.0f);
}

// One workgroup per batch element b. 256 threads = 4 waves:
//   half = t>>7:  half0 (waves 0,1) owns k in [0,64),  i in [0,16)
//                 half1 (waves 2,3) owns k in [64,128), i in [16,32)
//   h = t&127 : output hidden index this thread produces a partial for.
// Per step: all waves FMA their (k,i)-partial of hn[h]; half1 publishes its
// partial to LDS; barrier; half0 finalizes hn, applies the branchy tanh
// update, publishes h0 to LDS, and reduces score = hn.Wa and d = hn.Wd_slice
// (wave shuffles), storing per-wave partials straight to global (summed in
// kernel 2 -> no extra sync). half1 meanwhile runs the x-prefetch pipeline
// (4 steps ahead, register-staged, so HBM latency never hits the chain).
__global__ __launch_bounds__(256) void rnn_kernel(
    const float* __restrict__ x, const float* __restrict__ Wi,
    const float* __restrict__ bi, const float* __restrict__ Wh,
    const float* __restrict__ bh, const float* __restrict__ Wa,
    const float* __restrict__ Wd, const int* __restrict__ rdp,
    float2* __restrict__ part0, float2* __restrict__ part1)
{
    const int b    = blockIdx.x;
    const int t    = threadIdx.x;
    const int h    = t & 127;
    const int half = t >> 7;
    const int k0   = half << 6;   // 0 or 64
    const int i0   = half << 4;   // 0 or 16

    __shared__ __align__(16) float h0_lds[H_];
    __shared__ __align__(16) float x_lds[4][I_];
    __shared__ __align__(16) float partial_lds[H_];
    __shared__ __align__(16) float wd_lds[8 * H_];

    // ---- Preload weight columns into registers (one-time) ----
    float WhR[64];
#pragma unroll
    for (int j = 0; j < 64; ++j) WhR[j] = Wh[(k0 + j) * H_ + h];
    float WiR[16];
#pragma unroll
    for (int j = 0; j < 16; ++j) WiR[j] = Wi[(i0 + j) * H_ + h];
    const float waR   = Wa[h];
    const float biasR = bi[h] + bh[h];
    const int   rd    = rdp[0];

    // ---- LDS init ----
    if (t < H_) h0_lds[t] = 0.0f;
    for (int j = t; j < 8 * H_; j += 256)
        wd_lds[j] = Wd[((j >> 7) << 15) + (b << 7) + (j & 127)];

    // ---- x prefetch pipeline prime: slots 0..3 = steps 0..3 in LDS,
    //      xreg[0..3] = steps 4..7 in registers (written to LDS 4 steps later)
    float xreg[4];
    if (half == 1 && (t & 127) < I_) {
        const int i = t & 127;
        const float* xb = x + (size_t)b * S_ * I_;
#pragma unroll
        for (int j = 0; j < 4; ++j) x_lds[j][i] = xb[j * I_ + i];
#pragma unroll
        for (int j = 0; j < 4; ++j) xreg[j] = xb[(j + 4) * I_ + i];
    }
    sync_lds();

    float h0R = 0.0f, htR = 0.0f, hstartR = 0.0f;
    int cnt = 0;  // s % rd, maintained incrementally (no per-step division)

#pragma unroll 4
    for (int s = 0; s < S_; ++s) {
        // -------- phase 1: partial hn over my (k,i) ranges --------
        float a0 = 0.f, a1 = 0.f, a2 = 0.f, a3 = 0.f;
        const float4* h4p = (const float4*)(h0_lds + k0);
#pragma unroll
        for (int j = 0; j < 16; ++j) {
            float4 hv = h4p[j];
            a0 = fmaf(hv.x, WhR[4 * j + 0], a0);
            a1 = fmaf(hv.y, WhR[4 * j + 1], a1);
            a2 = fmaf(hv.z, WhR[4 * j + 2], a2);
            a3 = fmaf(hv.w, WhR[4 * j + 3], a3);
        }
        const float4* x4p = (const float4*)(&x_lds[s & 3][i0]);
#pragma unroll
        for (int j = 0; j < 4; ++j) {
            float4 xv = x4p[j];
            a0 = fmaf(xv.x, WiR[4 * j + 0], a0);
            a1 = fmaf(xv.y, WiR[4 * j + 1], a1);
            a2 = fmaf(xv.z, WiR[4 * j + 2], a2);
            a3 = fmaf(xv.w, WiR[4 * j + 3], a3);
        }
        float acc = (a0 + a1) + (a2 + a3);
        if (half == 1) partial_lds[h] = acc;
        sync_lds();  // Ba: half1 partial -> half0

        if (half == 0) {
            // -------- phase 2a: finalize hn, branchy state update --------
            float hn = acc + partial_lds[h] + biasR;
            float h0n;
            if (s == 0) {                      // br0: hstart=hn, h0 unchanged
                hstartR = hn;
                h0n = h0R;
            } else if (s == S_ - 2) {          // br1
                h0n = fast_tanh(hn + hstartR);
            } else if (rd == 1) {              // br4
                h0n = fast_tanh(hn + h0R);
            } else if (cnt == 0) {             // br2 (uses OLD ht, then ht=hn)
                h0n = fast_tanh(hn + htR);
                htR = hn;
            } else {                           // br3
                h0n = fast_tanh(hn);
            }
            h0R = h0n;
            h0_lds[h] = h0n;

            // -------- phase 2b: score & Wd-projection partial dots --------
            float p = hn * waR;
            float q = hn * wd_lds[((s & 7) << 7) + h];
#pragma unroll
            for (int off = 32; off > 0; off >>= 1) {
                p += __shfl_xor(p, off, 64);
                q += __shfl_xor(q, off, 64);
            }
            if ((t & 63) == 0) {   // t==0 -> h[0,64) partial, t==64 -> h[64,128)
                float2 v; v.x = p; v.y = q;
                ((t == 0) ? part0 : part1)[(s << 8) + b] = v;
            }
        } else {
            // -------- phase 2 (half1): x prefetch rotation --------
            if ((t & 127) < I_) {
                const int i = t & 127;
                x_lds[s & 3][i] = xreg[s & 3];          // x(s+4) into LDS
                int sx = s + 8; if (sx > S_ - 1) sx = S_ - 1;
                xreg[s & 3] = x[((size_t)b * S_ + sx) * I_ + i];  // fetch x(s+8)
            }
        }
        cnt = (cnt + 1 == rd) ? 0 : cnt + 1;
        sync_lds();  // Bb: h0 & x_lds visible for next step
    }
}

// out[r] = bd + sum_{f in chunk r} softmax(score)_f * d_f, chunk = 2048 flat
// (s,b) pairs with s in [8r,8r+8). ba is softmax-invariant -> omitted.
__global__ __launch_bounds__(256) void attn_kernel(
    const float2* __restrict__ part0, const float2* __restrict__ part1,
    const float* __restrict__ bd, float* __restrict__ out)
{
    const int r = blockIdx.x;
    const int t = threadIdx.x;
    float sc[8], dv[8];
    float mx = -1e30f;
#pragma unroll
    for (int u = 0; u < 8; ++u) {
        int f = (r << 11) + (u << 8) + t;
        float2 a = part0[f];
        float2 c = part1[f];
        sc[u] = a.x + c.x;
        dv[u] = a.y + c.y;
        mx = fmaxf(mx, sc[u]);
    }
    __shared__ float redm[4], redz[4], redw[4];
#pragma unroll
    for (int off = 32; off > 0; off >>= 1) mx = fmaxf(mx, __shfl_xor(mx, off, 64));
    if ((t & 63) == 0) redm[t >> 6] = mx;
    __syncthreads();
    mx = fmaxf(fmaxf(redm[0], redm[1]), fmaxf(redm[2], redm[3]));
    float z = 0.f, w = 0.f;
#pragma unroll
    for (int u = 0; u < 8; ++u) {
        float e = __expf(sc[u] - mx);
        z += e;
        w += e * dv[u];
    }
#pragma unroll
    for (int off = 32; off > 0; off >>= 1) {
        z += __shfl_xor(z, off, 64);
        w += __shfl_xor(w, off, 64);
    }
    if ((t & 63) == 0) { redz[t >> 6] = z; redw[t >> 6] = w; }
    __syncthreads();
    if (t == 0) {
        float Z = redz[0] + redz[1] + redz[2] + redz[3];
        float W = redw[0] + redw[1] + redw[2] + redw[3];
        out[r] = bd[0] + W / Z;
    }
}

extern "C" void kernel_launch(void* const* d_in, const int* in_sizes, int n_in,
                              void* d_out, int out_size, void* d_ws, size_t ws_size,
                              hipStream_t stream) {
    const float* x  = (const float*)d_in[0];
    const float* Wi = (const float*)d_in[1];
    const float* bi = (const float*)d_in[2];
    const float* Wh = (const float*)d_in[3];
    const float* bh = (const float*)d_in[4];
    const float* Wa = (const float*)d_in[5];
    // d_in[6] = ba: constant shift inside each softmax chunk -> no effect.
    const float* Wd = (const float*)d_in[7];
    const float* bd = (const float*)d_in[8];
    const int*  rdp = (const int*)d_in[9];

    // Workspace: two (S*B) float2 arrays of per-half {score, d} partials (8 MiB)
    float2* part0 = (float2*)d_ws;
    float2* part1 = part0 + (size_t)S_ * B_;

    rnn_kernel<<<B_, 256, 0, stream>>>(x, Wi, bi, Wh, bh, Wa, Wd, rdp, part0, part1);
    attn_kernel<<<B_, 256, 0, stream>>>(part0, part1, bd, (float*)d_out);
}

// Round 2
// 1495.225 us; speedup vs baseline: 1.2253x; 1.2253x over previous
//
#include <hip/hip_runtime.h>
#include <math.h>

// Problem constants (fixed by the reference): B=256, S=2048, I=32, H=128, O=1
#define B_ 256
#define S_ 2048
#define I_ 32
#define H_ 128

// Barrier WITHOUT vmcnt(0) drain (HIP __syncthreads waits vmcnt(0) before
// s_barrier, stalling on in-flight global prefetch/stores every step).
// LDS visibility only needs lgkmcnt(0).
__device__ __forceinline__ void sync_lds() {
    asm volatile("" ::: "memory");
    asm volatile("s_waitcnt lgkmcnt(0)" ::: "memory");
    __builtin_amdgcn_s_barrier();
    asm volatile("" ::: "memory");
}

// tanh(z) = 1 - 2/(e^{2z}+1); exact limits at +-inf, abs err ~1e-7.
__device__ __forceinline__ float fast_tanh(float z) {
    float e = __expf(2.0f * z);
    return 1.0f - 2.0f / (e + 1.0f);
}

// One workgroup (4 waves) per batch element. ONE barrier per step.
//   waves 0-1 (t<128, "compute"): full 128-k recurrence dot per thread
//     (Wh column in 128 VGPRs), + xw (precomputed by aux), tanh branch,
//     publish h0/hn to double-buffered LDS.
//   waves 2-3 ("aux"), one step behind on hn: score=hn.Wa and d=hn.Wd_slice
//     shuffle reductions (off the critical path now), x->LDS staging
//     (vector global loads; sync_lds doesn't drain vmcnt so they stay in
//     flight across barriers), and xw(s+2) = x.Wi + bias precompute.
__global__ __launch_bounds__(256, 1) void rnn_kernel(
    const float* __restrict__ x, const float* __restrict__ Wi,
    const float* __restrict__ bi, const float* __restrict__ Wh,
    const float* __restrict__ bh, const float* __restrict__ Wa,
    const float* __restrict__ Wd, const int* __restrict__ rdp,
    float2* __restrict__ part0, float2* __restrict__ part1)
{
    const int b = blockIdx.x;
    const int t = threadIdx.x;
    const int h = t & 127;
    const bool is_compute = (t < 128);

    __shared__ __align__(16) float h0_lds[2][H_];   // double-buffered state
    __shared__ __align__(16) float hn_lds[2][H_];   // hn for aux (1 step lag)
    __shared__ __align__(16) float xw_lds[4][H_];   // x.Wi+bias, 2 steps ahead
    __shared__ __align__(16) float xraw[8][I_];     // raw x rows, 4-8 ahead
    __shared__ __align__(16) float wd_lds[8 * H_];  // Wd slice for this batch

    // ---- common prologue ----
    const float biasR = bi[h] + bh[h];
    float WiC[32];
#pragma unroll
    for (int k = 0; k < 32; ++k) WiC[k] = Wi[k * H_ + h];
    const int rd = rdp[0];

    for (int j = t; j < 8 * H_; j += 256)
        wd_lds[j] = Wd[((j >> 7) << 15) + (b << 7) + (j & 127)];
    if (t < 128) {
        h0_lds[0][t] = 0.0f;
        // xraw rows 0..3
        xraw[t >> 5][t & 31] = x[((size_t)b * S_ + (t >> 5)) * I_ + (t & 31)];
    }

    float WhR[128];   // live only on compute threads
    float xr[4];      // live only on staging lanes (t in [128,160))
    float waR = 0.f;
    if (is_compute) {
#pragma unroll
        for (int k = 0; k < 128; ++k) WhR[k] = Wh[k * H_ + h];  // coalesced per k
    } else {
        waR = Wa[h];
        if (t < 160) {
            int lane = t - 128;
#pragma unroll
            for (int j = 0; j < 4; ++j)
                xr[j] = x[((size_t)b * S_ + 4 + j) * I_ + lane];  // x rows 4..7
        }
    }
    sync_lds();

    // xw(0) by compute threads, xw(1) by aux threads
    {
        int row = is_compute ? 0 : 1;
        const float4* xp = (const float4*)&xraw[row][0];
        float s0 = biasR;
#pragma unroll
        for (int j = 0; j < 8; ++j) {
            float4 v = xp[j];
            s0 = fmaf(v.x, WiC[4 * j + 0], s0);
            s0 = fmaf(v.y, WiC[4 * j + 1], s0);
            s0 = fmaf(v.z, WiC[4 * j + 2], s0);
            s0 = fmaf(v.w, WiC[4 * j + 3], s0);
        }
        xw_lds[row][h] = s0;
    }
    sync_lds();

    float h0R = 0.f, htR = 0.f, hstartR = 0.f;
    int cnt = 0;  // s % rd, incremental

#pragma unroll 4
    for (int s = 0; s < S_; ++s) {
        if (is_compute) {
            float xwv = xw_lds[s & 3][h];
            const float4* h4 = (const float4*)&h0_lds[s & 1][0];
            float a0 = 0.f, a1 = 0.f, a2 = 0.f, a3 = 0.f;
            float a4 = 0.f, a5 = 0.f, a6 = 0.f, a7 = 0.f;
#pragma unroll
            for (int j = 0; j < 32; j += 2) {
                float4 v = h4[j];
                a0 = fmaf(v.x, WhR[4 * j + 0], a0);
                a1 = fmaf(v.y, WhR[4 * j + 1], a1);
                a2 = fmaf(v.z, WhR[4 * j + 2], a2);
                a3 = fmaf(v.w, WhR[4 * j + 3], a3);
                float4 w = h4[j + 1];
                a4 = fmaf(w.x, WhR[4 * j + 4], a4);
                a5 = fmaf(w.y, WhR[4 * j + 5], a5);
                a6 = fmaf(w.z, WhR[4 * j + 6], a6);
                a7 = fmaf(w.w, WhR[4 * j + 7], a7);
            }
            float hn = ((a0 + a1) + (a2 + a3)) + ((a4 + a5) + (a6 + a7)) + xwv;
            hn_lds[s & 1][h] = hn;
            float h0n;
            if (s == 0) {                      // br0: hstart=hn, h0 unchanged
                hstartR = hn; h0n = h0R;
            } else if (s == S_ - 2) {          // br1
                h0n = fast_tanh(hn + hstartR);
            } else if (rd == 1) {              // br4
                h0n = fast_tanh(hn + h0R);
            } else if (cnt == 0) {             // br2 (old ht, then ht=hn)
                h0n = fast_tanh(hn + htR); htR = hn;
            } else {                           // br3
                h0n = fast_tanh(hn);
            }
            h0R = h0n;
            h0_lds[(s + 1) & 1][h] = h0n;
        } else {
            // -- x staging: write x(s+4) to LDS, fetch x(s+8) (vmcnt only) --
            if (t < 160) {
                int lane = t - 128;
                xraw[(s + 4) & 7][lane] = xr[s & 3];
                int sx = s + 8; if (sx > S_ - 1) sx = S_ - 1;
                xr[s & 3] = x[((size_t)b * S_ + sx) * I_ + lane];
            }
            // -- xw(s+2) = x(s+2).Wi + bias --
            {
                const float4* xp = (const float4*)&xraw[(s + 2) & 7][0];
                float s0 = biasR;
#pragma unroll
                for (int j = 0; j < 8; ++j) {
                    float4 v = xp[j];
                    s0 = fmaf(v.x, WiC[4 * j + 0], s0);
                    s0 = fmaf(v.y, WiC[4 * j + 1], s0);
                    s0 = fmaf(v.z, WiC[4 * j + 2], s0);
                    s0 = fmaf(v.w, WiC[4 * j + 3], s0);
                }
                xw_lds[(s + 2) & 3][h] = s0;
            }
            // -- hn(s-1) score/proj reduction (one step behind) --
            if (s > 0) {
                float hnv = hn_lds[(s - 1) & 1][h];
                float p = hnv * waR;
                float q = hnv * wd_lds[(((s - 1) & 7) << 7) + h];
#pragma unroll
                for (int off = 32; off > 0; off >>= 1) {
                    p += __shfl_xor(p, off, 64);
                    q += __shfl_xor(q, off, 64);
                }
                if ((t & 63) == 0) {  // t==128 -> h[0,64), t==192 -> h[64,128)
                    float2 v; v.x = p; v.y = q;
                    ((t == 128) ? part0 : part1)[((s - 1) << 8) + b] = v;
                }
            }
        }
        cnt = (cnt + 1 == rd) ? 0 : cnt + 1;
        sync_lds();
    }

    // epilogue: aux processes hn(S-1)
    if (!is_compute) {
        float hnv = hn_lds[(S_ - 1) & 1][h];
        float p = hnv * waR;
        float q = hnv * wd_lds[(((S_ - 1) & 7) << 7) + h];
#pragma unroll
        for (int off = 32; off > 0; off >>= 1) {
            p += __shfl_xor(p, off, 64);
            q += __shfl_xor(q, off, 64);
        }
        if ((t & 63) == 0) {
            float2 v; v.x = p; v.y = q;
            ((t == 128) ? part0 : part1)[((S_ - 1) << 8) + b] = v;
        }
    }
}

// out[r] = bd + sum_{f in chunk r} softmax(score)_f * d_f, chunk = 2048 flat
// (s,b) pairs with s in [8r,8r+8). ba is softmax-invariant -> omitted.
__global__ __launch_bounds__(256) void attn_kernel(
    const float2* __restrict__ part0, const float2* __restrict__ part1,
    const float* __restrict__ bd, float* __restrict__ out)
{
    const int r = blockIdx.x;
    const int t = threadIdx.x;
    float sc[8], dv[8];
    float mx = -1e30f;
#pragma unroll
    for (int u = 0; u < 8; ++u) {
        int f = (r << 11) + (u << 8) + t;
        float2 a = part0[f];
        float2 c = part1[f];
        sc[u] = a.x + c.x;
        dv[u] = a.y + c.y;
        mx = fmaxf(mx, sc[u]);
    }
    __shared__ float redm[4], redz[4], redw[4];
#pragma unroll
    for (int off = 32; off > 0; off >>= 1) mx = fmaxf(mx, __shfl_xor(mx, off, 64));
    if ((t & 63) == 0) redm[t >> 6] = mx;
    __syncthreads();
    mx = fmaxf(fmaxf(redm[0], redm[1]), fmaxf(redm[2], redm[3]));
    float z = 0.f, w = 0.f;
#pragma unroll
    for (int u = 0; u < 8; ++u) {
        float e = __expf(sc[u] - mx);
        z += e;
        w += e * dv[u];
    }
#pragma unroll
    for (int off = 32; off > 0; off >>= 1) {
        z += __shfl_xor(z, off, 64);
        w += __shfl_xor(w, off, 64);
    }
    if ((t & 63) == 0) { redz[t >> 6] = z; redw[t >> 6] = w; }
    __syncthreads();
    if (t == 0) {
        float Z = redz[0] + redz[1] + redz[2] + redz[3];
        float W = redw[0] + redw[1] + redw[2] + redw[3];
        out[r] = bd[0] + W / Z;
    }
}

extern "C" void kernel_launch(void* const* d_in, const int* in_sizes, int n_in,
                              void* d_out, int out_size, void* d_ws, size_t ws_size,
                              hipStream_t stream) {
    const float* x  = (const float*)d_in[0];
    const float* Wi = (const float*)d_in[1];
    const float* bi = (const float*)d_in[2];
    const float* Wh = (const float*)d_in[3];
    const float* bh = (const float*)d_in[4];
    const float* Wa = (const float*)d_in[5];
    // d_in[6] = ba: constant shift inside each softmax chunk -> no effect.
    const float* Wd = (const float*)d_in[7];
    const float* bd = (const float*)d_in[8];
    const int*  rdp = (const int*)d_in[9];

    // Workspace: two (S*B) float2 arrays of per-half {score, d} partials (8 MiB)
    float2* part0 = (float2*)d_ws;
    float2* part1 = part0 + (size_t)S_ * B_;

    rnn_kernel<<<B_, 256, 0, stream>>>(x, Wi, bi, Wh, bh, Wa, Wd, rdp, part0, part1);
    attn_kernel<<<B_, 256, 0, stream>>>(part0, part1, bd, (float*)d_out);
}

// Round 3
// 1255.128 us; speedup vs baseline: 1.4597x; 1.1913x over previous
//
#include <hip/hip_runtime.h>
#include <math.h>

// Problem constants (fixed by the reference): B=256, S=2048, I=32, H=128, O=1
#define B_ 256
#define S_ 2048
#define I_ 32
#define H_ 128

// Barrier WITHOUT vmcnt(0) drain (HIP __syncthreads waits vmcnt(0) before
// s_barrier, stalling on in-flight global prefetch/stores every step).
// LDS visibility only needs lgkmcnt(0).
__device__ __forceinline__ void sync_lds() {
    asm volatile("" ::: "memory");
    asm volatile("s_waitcnt lgkmcnt(0)" ::: "memory");
    __builtin_amdgcn_s_barrier();
    asm volatile("" ::: "memory");
}

// tanh(z) = 1 - 2/(e^{2z}+1); exact limits at +-inf, abs err ~1e-7.
__device__ __forceinline__ float fast_tanh(float z) {
    float e = __expf(2.0f * z);
    return 1.0f - 2.0f / (e + 1.0f);
}

// Full-wave (64-lane) sum via DPP adds -- VALU pipe only, NO LDS traffic
// (HIP __shfl_xor lowers to ds_swizzle which occupies the shared LDS pipe).
// Result valid in lane 63. Canonical GCN sequence: row_shr 1/2/4/8 then
// row_bcast:15 (rows 1,3) and row_bcast:31 (rows 2,3).
__device__ __forceinline__ float dpp_red_sum64(float v) {
    float t;
    t = __int_as_float(__builtin_amdgcn_update_dpp(0, __float_as_int(v), 0x111, 0xf, 0xf, false)); v += t;
    t = __int_as_float(__builtin_amdgcn_update_dpp(0, __float_as_int(v), 0x112, 0xf, 0xf, false)); v += t;
    t = __int_as_float(__builtin_amdgcn_update_dpp(0, __float_as_int(v), 0x114, 0xf, 0xf, false)); v += t;
    t = __int_as_float(__builtin_amdgcn_update_dpp(0, __float_as_int(v), 0x118, 0xf, 0xf, false)); v += t;
    t = __int_as_float(__builtin_amdgcn_update_dpp(0, __float_as_int(v), 0x142, 0xa, 0xf, false)); v += t;
    t = __int_as_float(__builtin_amdgcn_update_dpp(0, __float_as_int(v), 0x143, 0xc, 0xf, false)); v += t;
    return v;
}

// One workgroup (4 waves) per batch element; ONE barrier per step.
// Compute waves 0-1 (t<128), lane = (kg = l&7, hg = (l>>3)+8w):
//   reads h0 k-slice (4 x b128, 8-way same-address broadcast, bank-spread by
//   k-remap k = 4kg + 32j + c), 128 FMAs vs register Wh, writes 8 partials to
//   pt[h][9] (padded; 2-way banks), reads back row h=64w+l (2 x b128,
//   wave-private -> no barrier), + xw, tanh branch, publish h0/hn.
// Aux waves 2-3: xw(s+2)=x.Wi+bias from a 2-slot register x buffer (direct
//   global loads, 2-step prefetch, vmcnt never drained by sync_lds);
//   score/proj dots on hn(s-1) via DPP reduction; store straight to global.
__global__ __launch_bounds__(256, 1) void rnn_kernel(
    const float* __restrict__ x, const float* __restrict__ Wi,
    const float* __restrict__ bi, const float* __restrict__ Wh,
    const float* __restrict__ bh, const float* __restrict__ Wa,
    const float* __restrict__ Wd, const int* __restrict__ rdp,
    float2* __restrict__ part0, float2* __restrict__ part1)
{
    const int b = blockIdx.x;
    const int t = threadIdx.x;
    const bool is_compute = (t < 128);

    __shared__ __align__(16) float h0_lds[2][H_];
    __shared__ __align__(16) float hn_lds[2][H_];
    __shared__ __align__(16) float xw_lds[4][H_];
    __shared__ __align__(16) float pt[H_][9];      // pad 9: contiguous row read
    __shared__ __align__(16) float wd_lds[8 * H_];

    const int rd = rdp[0];
    for (int j = t; j < 8 * H_; j += 256)
        wd_lds[j] = Wd[((j >> 7) << 15) + (b << 7) + (j & 127)];
    if (t < 128) h0_lds[0][t] = 0.0f;

    // ---- compute-lane mapping & weights ----
    const int w    = (t >> 6) & 1;       // compute wave id
    const int l    = t & 63;
    const int kg   = l & 7;              // k-group (owns k = 4kg+32j+c)
    const int hg   = (l >> 3) + 8 * w;   // h-group (8 h)
    const int hred = 64 * w + l;         // h this lane finalizes

    float WhR[128];
    if (is_compute) {
#pragma unroll
        for (int c = 0; c < 16; ++c) {
            int k = 4 * kg + 32 * (c >> 2) + (c & 3);
            const float4* wrow = (const float4*)(Wh + k * H_ + 8 * hg);
            float4 w0 = wrow[0], w1 = wrow[1];
            WhR[c * 8 + 0] = w0.x; WhR[c * 8 + 1] = w0.y;
            WhR[c * 8 + 2] = w0.z; WhR[c * 8 + 3] = w0.w;
            WhR[c * 8 + 4] = w1.x; WhR[c * 8 + 5] = w1.y;
            WhR[c * 8 + 6] = w1.z; WhR[c * 8 + 7] = w1.w;
        }
    }

    // ---- aux prologue ----
    const int h = t & 127;
    float waR = 0.f, biasR = 0.f;
    float WiC[32];
    float4 xb[2][8];   // x(s+2) register pipeline, 2 slots
    if (!is_compute) {
        biasR = bi[h] + bh[h];
        waR = Wa[h];
#pragma unroll
        for (int k = 0; k < 32; ++k) WiC[k] = Wi[k * H_ + h];
        const float* xrow0 = x + (size_t)b * S_ * I_;
#pragma unroll
        for (int r = 0; r < 2; ++r) {   // xw(0), xw(1)
            const float4* xr4 = (const float4*)(xrow0 + r * I_);
            float s0 = biasR;
#pragma unroll
            for (int j = 0; j < 8; ++j) {
                float4 v = xr4[j];
                s0 = fmaf(v.x, WiC[4 * j + 0], s0);
                s0 = fmaf(v.y, WiC[4 * j + 1], s0);
                s0 = fmaf(v.z, WiC[4 * j + 2], s0);
                s0 = fmaf(v.w, WiC[4 * j + 3], s0);
            }
            xw_lds[r][h] = s0;
        }
#pragma unroll
        for (int j = 0; j < 8; ++j) xb[0][j] = ((const float4*)(xrow0 + 2 * I_))[j];
#pragma unroll
        for (int j = 0; j < 8; ++j) xb[1][j] = ((const float4*)(xrow0 + 3 * I_))[j];
    }
    sync_lds();

    float h0R = 0.f, htR = 0.f, hstartR = 0.f;
    int cnt = 0;  // s % rd, incremental

#pragma unroll 4
    for (int s = 0; s < S_; ++s) {
        if (is_compute) {
            // h0 k-slice: floats {4kg+32j .. +3}, j=0..3 (banks 4kg..4kg+3)
            const float4* hsrc = (const float4*)&h0_lds[s & 1][0];
            float4 hv[4];
#pragma unroll
            for (int j = 0; j < 4; ++j) hv[j] = hsrc[kg + 8 * j];
            const float* hvf = (const float*)hv;
            float acc[8];
#pragma unroll
            for (int j = 0; j < 8; ++j) acc[j] = 0.f;
#pragma unroll
            for (int c = 0; c < 16; ++c) {
                float hval = hvf[c];
#pragma unroll
                for (int j = 0; j < 8; ++j)
                    acc[j] = fmaf(hval, WhR[c * 8 + j], acc[j]);
            }
#pragma unroll
            for (int j = 0; j < 8; ++j) pt[8 * hg + j][kg] = acc[j];
            // wave-private read-back (compiler inserts lgkmcnt wait)
            float4 r0 = *(const float4*)&pt[hred][0];
            float4 r1 = *(const float4*)&pt[hred][4];
            float hn = ((r0.x + r0.y) + (r0.z + r0.w)) +
                       ((r1.x + r1.y) + (r1.z + r1.w)) + xw_lds[s & 3][hred];
            hn_lds[s & 1][hred] = hn;
            float h0n;
            if (s == 0) {                      // br0: hstart=hn, h0 unchanged
                hstartR = hn; h0n = h0R;
            } else if (s == S_ - 2) {          // br1
                h0n = fast_tanh(hn + hstartR);
            } else if (rd == 1) {              // br4
                h0n = fast_tanh(hn + h0R);
            } else if (cnt == 0) {             // br2 (old ht, then ht=hn)
                h0n = fast_tanh(hn + htR); htR = hn;
            } else {                           // br3
                h0n = fast_tanh(hn);
            }
            h0R = h0n;
            h0_lds[(s + 1) & 1][hred] = h0n;
        } else {
            // xw(s+2) from register slot (loaded 2 steps ago)
            float s0 = biasR;
#pragma unroll
            for (int j = 0; j < 8; ++j) {
                float4 v = xb[s & 1][j];
                s0 = fmaf(v.x, WiC[4 * j + 0], s0);
                s0 = fmaf(v.y, WiC[4 * j + 1], s0);
                s0 = fmaf(v.z, WiC[4 * j + 2], s0);
                s0 = fmaf(v.w, WiC[4 * j + 3], s0);
            }
            xw_lds[(s + 2) & 3][h] = s0;
            // refill slot with x(s+4) (in flight across barriers; vmcnt-tracked)
            {
                int sx = s + 4; if (sx > S_ - 1) sx = S_ - 1;
                const float4* xr4 = (const float4*)(x + ((size_t)b * S_ + sx) * I_);
#pragma unroll
                for (int j = 0; j < 8; ++j) xb[s & 1][j] = xr4[j];
            }
            // score/proj dots on hn(s-1), DPP reduce (VALU only)
            if (s > 0) {
                float hnv = hn_lds[(s - 1) & 1][h];
                float p = hnv * waR;
                float q = hnv * wd_lds[(((s - 1) & 7) << 7) + h];
                p = dpp_red_sum64(p);
                q = dpp_red_sum64(q);
                if ((t & 63) == 63) {   // t==191 -> h[0,64), t==255 -> h[64,128)
                    float2 vv; vv.x = p; vv.y = q;
                    ((t == 191) ? part0 : part1)[((s - 1) << 8) + b] = vv;
                }
            }
        }
        cnt = (cnt + 1 == rd) ? 0 : cnt + 1;
        sync_lds();
    }

    // epilogue: hn(S-1)
    if (!is_compute) {
        float hnv = hn_lds[(S_ - 1) & 1][h];
        float p = hnv * waR;
        float q = hnv * wd_lds[(((S_ - 1) & 7) << 7) + h];
        p = dpp_red_sum64(p);
        q = dpp_red_sum64(q);
        if ((t & 63) == 63) {
            float2 vv; vv.x = p; vv.y = q;
            ((t == 191) ? part0 : part1)[((S_ - 1) << 8) + b] = vv;
        }
    }
}

// out[r] = bd + sum_{f in chunk r} softmax(score)_f * d_f, chunk = 2048 flat
// (s,b) pairs with s in [8r,8r+8). ba is softmax-invariant -> omitted.
__global__ __launch_bounds__(256) void attn_kernel(
    const float2* __restrict__ part0, const float2* __restrict__ part1,
    const float* __restrict__ bd, float* __restrict__ out)
{
    const int r = blockIdx.x;
    const int t = threadIdx.x;
    float sc[8], dv[8];
    float mx = -1e30f;
#pragma unroll
    for (int u = 0; u < 8; ++u) {
        int f = (r << 11) + (u << 8) + t;
        float2 a = part0[f];
        float2 c = part1[f];
        sc[u] = a.x + c.x;
        dv[u] = a.y + c.y;
        mx = fmaxf(mx, sc[u]);
    }
    __shared__ float redm[4], redz[4], redw[4];
#pragma unroll
    for (int off = 32; off > 0; off >>= 1) mx = fmaxf(mx, __shfl_xor(mx, off, 64));
    if ((t & 63) == 0) redm[t >> 6] = mx;
    __syncthreads();
    mx = fmaxf(fmaxf(redm[0], redm[1]), fmaxf(redm[2], redm[3]));
    float z = 0.f, w = 0.f;
#pragma unroll
    for (int u = 0; u < 8; ++u) {
        float e = __expf(sc[u] - mx);
        z += e;
        w += e * dv[u];
    }
#pragma unroll
    for (int off = 32; off > 0; off >>= 1) {
        z += __shfl_xor(z, off, 64);
        w += __shfl_xor(w, off, 64);
    }
    if ((t & 63) == 0) { redz[t >> 6] = z; redw[t >> 6] = w; }
    __syncthreads();
    if (t == 0) {
        float Z = redz[0] + redz[1] + redz[2] + redz[3];
        float W = redw[0] + redw[1] + redw[2] + redw[3];
        out[r] = bd[0] + W / Z;
    }
}

extern "C" void kernel_launch(void* const* d_in, const int* in_sizes, int n_in,
                              void* d_out, int out_size, void* d_ws, size_t ws_size,
                              hipStream_t stream) {
    const float* x  = (const float*)d_in[0];
    const float* Wi = (const float*)d_in[1];
    const float* bi = (const float*)d_in[2];
    const float* Wh = (const float*)d_in[3];
    const float* bh = (const float*)d_in[4];
    const float* Wa = (const float*)d_in[5];
    // d_in[6] = ba: constant shift inside each softmax chunk -> no effect.
    const float* Wd = (const float*)d_in[7];
    const float* bd = (const float*)d_in[8];
    const int*  rdp = (const int*)d_in[9];

    // Workspace: two (S*B) float2 arrays of per-half {score, d} partials (8 MiB)
    float2* part0 = (float2*)d_ws;
    float2* part1 = part0 + (size_t)S_ * B_;

    rnn_kernel<<<B_, 256, 0, stream>>>(x, Wi, bi, Wh, bh, Wa, Wd, rdp, part0, part1);
    attn_kernel<<<B_, 256, 0, stream>>>(part0, part1, bd, (float*)d_out);
}